// Round 13
// baseline (57.159 us; speedup 1.0000x reference)
//
#include <hip/hip_runtime.h>
#include <hip/hip_bf16.h>
#include <math.h>

#define NROW 4096
#define CDIM 256
#define KSEL 20

typedef __attribute__((ext_vector_type(8))) short short8_t;  // 8 bf16 (4 VGPRs)
typedef __attribute__((ext_vector_type(4))) float f32x4;

__device__ __forceinline__ unsigned sad_u8(unsigned a, unsigned b, unsigned c) {
    unsigned d;
    asm("v_sad_u8 %0, %1, %2, %3" : "=v"(d) : "v"(a), "v"(b), "v"(c));
    return d;
}

// cvt 8 f32 -> 8 bf16 (RNE), accumulate sum of squares, 16B LDS store
__device__ __forceinline__ void cvt_store(ushort* dst, float4 x, float4 y, float& ssq) {
    ssq += x.x * x.x + x.y * x.y + x.z * x.z + x.w * x.w
         + y.x * y.x + y.y * y.y + y.z * y.z + y.w * y.w;
    union { ushort u[8]; short8_t v; } p;
    __hip_bfloat16 h;
    h = __float2bfloat16(x.x); p.u[0] = *(ushort*)&h;
    h = __float2bfloat16(x.y); p.u[1] = *(ushort*)&h;
    h = __float2bfloat16(x.z); p.u[2] = *(ushort*)&h;
    h = __float2bfloat16(x.w); p.u[3] = *(ushort*)&h;
    h = __float2bfloat16(y.x); p.u[4] = *(ushort*)&h;
    h = __float2bfloat16(y.y); p.u[5] = *(ushort*)&h;
    h = __float2bfloat16(y.z); p.u[6] = *(ushort*)&h;
    h = __float2bfloat16(y.w); p.u[7] = *(ushort*)&h;
    *(short8_t*)dst = p.v;
}

// ---------------------------------------------------------------------------
// Kernel 1: fused normalize + bf16 MFMA GEMM. 128x128 tile, BK=32,
// double-buffered LDS, reg-staged f32->bf16 (loads issued before the MFMA
// cluster, writes after: T14 split). Row norms accumulated during staging
// (ssq of the exact f32 values), applied in the epilogue:
// d = (1 - acc * rinvA[i] * rinvB[j]) * 0.5 -> 7-bit u8 key.
// ---------------------------------------------------------------------------
__global__ __launch_bounds__(256, 3) void gemmn_kernel(const float* __restrict__ A,
                                                       const float* __restrict__ B,
                                                       unsigned char* __restrict__ dist8) {
    const int tid  = threadIdx.x;
    const int lane = tid & 63;
    const int wid  = tid >> 6;
    const int wm = wid >> 1, wn = wid & 1;

    const int flat = blockIdx.x;                       // 0..1023
    const int wg   = (flat & 7) * 128 + (flat >> 3);   // bijective XCD swizzle
    const int j0   = (wg & 31) * 128;
    const int i0   = (wg >> 5) * 128;
    const int lr  = lane & 15;
    const int lk8 = (lane >> 4) * 8;

    __shared__ __align__(16) ushort As[2][4096];   // 2 x 8 KB (128 x 32)
    __shared__ __align__(16) ushort Bs[2][4096];   // 2 x 8 KB
    __shared__ float rinvA[128], rinvB[128];       // 1 KB

    // staging: thread covers rows {srow, 64+srow}, cols scol..scol+8 per K-step
    const int srow = tid >> 2;        // 0..63
    const int scol = (tid & 3) * 8;   // 0,8,16,24
    const float* __restrict__ ga0 = A + (size_t)(i0 + srow) * CDIM + scol;
    const float* __restrict__ ga1 = A + (size_t)(i0 + 64 + srow) * CDIM + scol;
    const float* __restrict__ gb0 = B + (size_t)(j0 + srow) * CDIM + scol;
    const float* __restrict__ gb1 = B + (size_t)(j0 + 64 + srow) * CDIM + scol;

    float ssa0 = 0.f, ssa1 = 0.f, ssb0 = 0.f, ssb1 = 0.f;
    float4 la0a, la0b, la1a, la1b, lb0a, lb0b, lb1a, lb1b;

    f32x4 acc[4][4];
#pragma unroll
    for (int m = 0; m < 4; ++m)
#pragma unroll
        for (int n = 0; n < 4; ++n) acc[m][n] = (f32x4){0.f, 0.f, 0.f, 0.f};

#define STAGE_LOAD(K0)                                                        \
    {                                                                         \
        la0a = *(const float4*)(ga0 + (K0));  la0b = *(const float4*)(ga0 + (K0) + 4); \
        la1a = *(const float4*)(ga1 + (K0));  la1b = *(const float4*)(ga1 + (K0) + 4); \
        lb0a = *(const float4*)(gb0 + (K0));  lb0b = *(const float4*)(gb0 + (K0) + 4); \
        lb1a = *(const float4*)(gb1 + (K0));  lb1b = *(const float4*)(gb1 + (K0) + 4); \
    }

#define STAGE_WRITE(BUF)                                                      \
    {                                                                         \
        cvt_store(&As[BUF][srow * 32 + scol],        la0a, la0b, ssa0);       \
        cvt_store(&As[BUF][(64 + srow) * 32 + scol], la1a, la1b, ssa1);       \
        cvt_store(&Bs[BUF][srow * 32 + scol],        lb0a, lb0b, ssb0);       \
        cvt_store(&Bs[BUF][(64 + srow) * 32 + scol], lb1a, lb1b, ssb1);       \
    }

    // prologue: stage K-tile 0 into buffer 0
    STAGE_LOAD(0);
    STAGE_WRITE(0);
    __syncthreads();

#pragma unroll
    for (int ks = 0; ks < 8; ++ks) {
        const int cur = ks & 1;
        if (ks < 7) STAGE_LOAD((ks + 1) * 32);   // issue loads early
        // compute current buffer: 8 ds_read_b128 + 16 MFMA
        {
            short8_t a[4], b[4];
#pragma unroll
            for (int m = 0; m < 4; ++m)
                a[m] = *(const short8_t*)&As[cur][(wm * 64 + m * 16 + lr) * 32 + lk8];
#pragma unroll
            for (int n = 0; n < 4; ++n)
                b[n] = *(const short8_t*)&Bs[cur][(wn * 64 + n * 16 + lr) * 32 + lk8];
#pragma unroll
            for (int m = 0; m < 4; ++m)
#pragma unroll
                for (int n = 0; n < 4; ++n)
                    acc[m][n] = __builtin_amdgcn_mfma_f32_16x16x32_bf16(a[m], b[n], acc[m][n], 0, 0, 0);
        }
        if (ks < 7) STAGE_WRITE(cur ^ 1);        // vmcnt wait lands after MFMA
        __syncthreads();
    }

    // row-norm finish: combine the 4 lanes sharing each row (lanes 4r..4r+3)
    ssa0 += __shfl_xor(ssa0, 1, 64); ssa0 += __shfl_xor(ssa0, 2, 64);
    ssa1 += __shfl_xor(ssa1, 1, 64); ssa1 += __shfl_xor(ssa1, 2, 64);
    ssb0 += __shfl_xor(ssb0, 1, 64); ssb0 += __shfl_xor(ssb0, 2, 64);
    ssb1 += __shfl_xor(ssb1, 1, 64); ssb1 += __shfl_xor(ssb1, 2, 64);
    if ((tid & 3) == 0) {
        rinvA[srow]      = 1.0f / fmaxf(sqrtf(ssa0), 1e-12f);
        rinvA[64 + srow] = 1.0f / fmaxf(sqrtf(ssa1), 1e-12f);
        rinvB[srow]      = 1.0f / fmaxf(sqrtf(ssb0), 1e-12f);
        rinvB[64 + srow] = 1.0f / fmaxf(sqrtf(ssb1), 1e-12f);
    }
    __syncthreads();

    // epilogue: scale, 7-bit quantize, byte store (row=(lane>>4)*4+q, col=lane&15)
    const int orow = (lane >> 4) * 4;
    const int ocol = lane & 15;
    float rb[4];
#pragma unroll
    for (int n = 0; n < 4; ++n) rb[n] = rinvB[wn * 64 + n * 16 + ocol];
#pragma unroll
    for (int m = 0; m < 4; ++m)
#pragma unroll
        for (int q = 0; q < 4; ++q) {
            const int irow = wm * 64 + m * 16 + orow + q;   // tile-local row
            const float ra = rinvA[irow];
#pragma unroll
            for (int n = 0; n < 4; ++n) {
                float d = (1.0f - acc[m][n][q] * ra * rb[n]) * 0.5f;
                d = fminf(fmaxf(d, 0.0f), 1.0f);
                unsigned key = __float2uint_rn(d * 127.0f);
                dist8[(size_t)(i0 + irow) * NROW + (j0 + wn * 64 + n * 16 + ocol)] = (unsigned char)key;
            }
        }
#undef STAGE_LOAD
#undef STAGE_WRITE
}

// ---------------------------------------------------------------------------
// Kernel 2: per-row top-K on 7-bit keys (verified SWAR body, round 10/12),
// with VGPR pin against rematerialization (round-9 lesson).
// ---------------------------------------------------------------------------
__global__ __launch_bounds__(256) void select_kernel(const unsigned char* __restrict__ dist8,
                                                     float* __restrict__ loss) {
    const int tid  = threadIdx.x;
    const int lane = tid & 63;
    const int wid  = tid >> 6;
    const int row  = blockIdx.x * 4 + wid;

    const uint4* __restrict__ P = (const uint4*)(dist8 + (size_t)row * NROW);
    unsigned w[16];
#pragma unroll
    for (int i = 0; i < 4; ++i) {
        uint4 v = P[i * 64 + lane];
        w[4 * i + 0] = v.x; w[4 * i + 1] = v.y;
        w[4 * i + 2] = v.z; w[4 * i + 3] = v.w;
    }
    // pin into registers: compiler may no longer re-derive w[] from memory
#pragma unroll
    for (int i = 0; i < 16; ++i) asm volatile("" : "+v"(w[i]));

    const unsigned dku = (unsigned)dist8[(size_t)row * NROW + row];
    const unsigned M = 0x80808080u;
    const unsigned zero = 0u;

    unsigned rs = 0;
#pragma unroll
    for (int i = 0; i < 16; ++i) rs = sad_u8(w[i], zero, rs);

    int lo1 = 0, hi1 = 128, clo = 0;   // min: largest T with cnt(<T) < K
    int lo2 = -1, hi2 = 127, chi = 0;  // max: smallest T with cnt(>T) < K
#pragma unroll 1
    for (int it = 0; it < 7; ++it) {
        const int mid1 = (lo1 + hi1) >> 1;
        const int mid2 = (lo2 + hi2) >> 1;
        const unsigned C1 = (unsigned)(127 + mid1) * 0x01010101u;
        const unsigned C2 = (unsigned)(128 + mid2) * 0x01010101u;
        unsigned a1 = 0, a2 = 0;
#pragma unroll
        for (int i = 0; i < 16; ++i) {
            a1 = sad_u8((C1 - w[i]) & M, zero, a1);
            a2 = sad_u8((C2 - w[i]) & M, zero, a2);
        }
        int cc = (int)((a1 >> 7) | ((a2 >> 7) << 16));
#pragma unroll
        for (int off = 32; off; off >>= 1) cc += __shfl_xor(cc, off, 64);
        cc = __builtin_amdgcn_readfirstlane(cc);
        const int c1 = (cc & 0xFFFF) - ((dku < (unsigned)mid1) ? 1 : 0);
        const int c2 = (4096 - (cc >> 16)) - (((int)dku > mid2) ? 1 : 0);
        if (c1 < KSEL) { lo1 = mid1; clo = c1; } else hi1 = mid1;
        if (c2 < KSEL) { hi2 = mid2; chi = c2; } else lo2 = mid2;
    }
    const int Tmin = lo1, Tmax = hi2;

    const unsigned CA = (unsigned)(127 + Tmin) * 0x01010101u;
    const unsigned CB = (unsigned)(128 + Tmax) * 0x01010101u;
    unsigned sA = 0, sB = 0;
#pragma unroll
    for (int i = 0; i < 16; ++i) {
        const unsigned mA = ((CA - w[i]) & M) >> 7;
        sA = sad_u8(w[i] & ((mA << 8) - mA), zero, sA);
        const unsigned mB = ((CB - w[i]) & M) >> 7;
        sB = sad_u8(w[i] & ((mB << 8) - mB), zero, sB);
    }
#pragma unroll
    for (int off = 32; off; off >>= 1) {
        rs += __shfl_xor(rs, off, 64);
        sA += __shfl_xor(sA, off, 64);
        sB += __shfl_xor(sB, off, 64);
    }

    const int sum_min_i = (int)sA - ((dku < (unsigned)Tmin) ? (int)dku : 0)
                        + (KSEL - clo) * Tmin;
    const int sum_gt    = (int)(rs - sB);
    const int sum_max_i = sum_gt - (((int)dku > Tmax) ? (int)dku : 0)
                        + (KSEL - chi) * Tmax;

    if (lane == 0) {
        const float inv = 1.0f / 127.0f;
        const float total = (float)(sum_min_i + sum_max_i) * inv;
        const float dap = (float)dku * inv;
        const float neg = -0.0125f * total;  // -((1-prior)/(2K)) * sum
        const float pos = 0.5f * dap;        // prior * dist_ap
        loss[row] = (neg < 0.f) ? -neg : (pos + neg);
    }
}

// ---------------------------------------------------------------------------
// Kernel 3: deterministic mean of loss[0..N-1] -> out[0]
// ---------------------------------------------------------------------------
__global__ __launch_bounds__(256) void finalize_kernel(const float* __restrict__ loss,
                                                       float* __restrict__ out) {
    const int tid = threadIdx.x;
    float s = 0.f;
    for (int k = tid; k < NROW; k += 256) s += loss[k];
#pragma unroll
    for (int off = 32; off; off >>= 1) s += __shfl_xor(s, off, 64);
    __shared__ float p[4];
    if ((tid & 63) == 0) p[tid >> 6] = s;
    __syncthreads();
    if (tid == 0) out[0] = (p[0] + p[1] + p[2] + p[3]) * (1.0f / (float)NROW);
}

// ---------------------------------------------------------------------------
extern "C" void kernel_launch(void* const* d_in, const int* in_sizes, int n_in,
                              void* d_out, int out_size, void* d_ws, size_t ws_size,
                              hipStream_t stream) {
    const float* A = (const float*)d_in[0];  // input  [N,C] f32
    const float* B = (const float*)d_in[1];  // target [N,C] f32

    char* ws = (char*)d_ws;
    float* lossv = (float*)ws;                                  // 16 KB
    unsigned char* dist8 = (unsigned char*)(ws + (size_t)NROW * 4);  // 16 MB
    float* outp = (float*)d_out;

    gemmn_kernel<<<1024, 256, 0, stream>>>(A, B, dist8);
    select_kernel<<<NROW / 4, 256, 0, stream>>>(dist8, lossv);
    finalize_kernel<<<1, 256, 0, stream>>>(lossv, outp);
}

// Round 14
// 44.285 us; speedup vs baseline: 1.2907x; 1.2907x over previous
//
#include <hip/hip_runtime.h>
#include <hip/hip_bf16.h>
#include <math.h>

#define NROW 4096
#define CDIM 256
#define KSEL 20

typedef __attribute__((ext_vector_type(8))) short short8_t;  // 8 bf16 (4 VGPRs)
typedef __attribute__((ext_vector_type(4))) float f32x4;
typedef const __attribute__((address_space(1))) unsigned g_u32;
typedef __attribute__((address_space(3))) unsigned l_u32;

__device__ __forceinline__ unsigned sad_u8(unsigned a, unsigned b, unsigned c) {
    unsigned d;
    asm("v_sad_u8 %0, %1, %2, %3" : "=v"(d) : "v"(a), "v"(b), "v"(c));
    return d;
}

// ---------------------------------------------------------------------------
// Kernel 1: normalize rows of A and B -> bf16 (verified rounds 6-12).
// ---------------------------------------------------------------------------
__global__ __launch_bounds__(256) void prep_kernel(const float* __restrict__ A,
                                                   const float* __restrict__ B,
                                                   ushort* __restrict__ An,
                                                   ushort* __restrict__ Bn) {
    const int tid  = threadIdx.x;
    const int lane = tid & 63;
    const int wid  = tid >> 6;
    const int r    = blockIdx.x * 4 + wid;   // 0..8191
    const int row  = r & (NROW - 1);
    const float* __restrict__ X = (r < NROW) ? A : B;
    ushort* __restrict__ Y = (r < NROW) ? An : Bn;

    const float4 v = ((const float4*)(X + (size_t)row * CDIM))[lane];
    float s = v.x * v.x + v.y * v.y + v.z * v.z + v.w * v.w;
#pragma unroll
    for (int off = 32; off; off >>= 1) s += __shfl_xor(s, off, 64);
    const float rinv = 1.0f / fmaxf(sqrtf(s), 1e-12f);

    ushort4 o;
    __hip_bfloat16 h0 = __float2bfloat16(v.x * rinv); o.x = *(ushort*)&h0;
    __hip_bfloat16 h1 = __float2bfloat16(v.y * rinv); o.y = *(ushort*)&h1;
    __hip_bfloat16 h2 = __float2bfloat16(v.z * rinv); o.z = *(ushort*)&h2;
    __hip_bfloat16 h3 = __float2bfloat16(v.w * rinv); o.w = *(ushort*)&h3;
    ((ushort4*)(Y + (size_t)row * CDIM))[lane] = o;
}

// ---------------------------------------------------------------------------
// Kernel 2: bf16 MFMA GEMM, 128x128 tile, BK=32, double-buffered LDS via
// global_load_lds (32 KB/block -> 4 blocks/CU; verified round 12).
// Bijective XCD swizzle. dist -> 7-bit u8 keys.
// ---------------------------------------------------------------------------
__global__ __launch_bounds__(256) void gemm16_kernel(const ushort* __restrict__ An,
                                                     const ushort* __restrict__ Bn,
                                                     unsigned char* __restrict__ dist8) {
    const int tid  = threadIdx.x;
    const int lane = tid & 63;
    const int wid  = tid >> 6;
    const int wm = wid >> 1, wn = wid & 1;

    const int flat = blockIdx.x;                       // 0..1023
    const int wg   = (flat & 7) * 128 + (flat >> 3);   // bijective XCD swizzle
    const int j0   = (wg & 31) * 128;
    const int i0   = (wg >> 5) * 128;
    const int lr  = lane & 15;
    const int lk8 = (lane >> 4) * 8;

    __shared__ __align__(16) ushort As[2][4096];   // 2 x 8 KB (128 x 32)
    __shared__ __align__(16) ushort Bs[2][4096];   // 2 x 8 KB

    // staging: thread t covers 16B: row (t>>2) + r*64, col8 (t&3)*8 of 128x32 tile
    const int srow = tid >> 2;        // 0..63
    const int scol = (tid & 3) * 8;   // 0,8,16,24
    const unsigned wbase = (unsigned)(wid * 1024);  // wave-uniform LDS byte base

    f32x4 acc[4][4];
#pragma unroll
    for (int m = 0; m < 4; ++m)
#pragma unroll
        for (int n = 0; n < 4; ++n) acc[m][n] = (f32x4){0.f, 0.f, 0.f, 0.f};

    // prologue: stage K-tile 0 into buffer 0
#pragma unroll
    for (int r = 0; r < 2; ++r) {
        const ushort* ga = An + (size_t)(i0 + r * 64 + srow) * CDIM + scol;
        __builtin_amdgcn_global_load_lds((g_u32*)ga,
            (l_u32*)((char*)As[0] + r * 4096 + wbase), 16, 0, 0);
        const ushort* gb = Bn + (size_t)(j0 + r * 64 + srow) * CDIM + scol;
        __builtin_amdgcn_global_load_lds((g_u32*)gb,
            (l_u32*)((char*)Bs[0] + r * 4096 + wbase), 16, 0, 0);
    }
    __syncthreads();

#pragma unroll
    for (int ks = 0; ks < 8; ++ks) {
        const int cur = ks & 1;
        if (ks < 7) {   // stage next K-tile into other buffer (overlaps MFMA)
            const int k0 = (ks + 1) * 32;
#pragma unroll
            for (int r = 0; r < 2; ++r) {
                const ushort* ga = An + (size_t)(i0 + r * 64 + srow) * CDIM + k0 + scol;
                __builtin_amdgcn_global_load_lds((g_u32*)ga,
                    (l_u32*)((char*)As[cur ^ 1] + r * 4096 + wbase), 16, 0, 0);
                const ushort* gb = Bn + (size_t)(j0 + r * 64 + srow) * CDIM + k0 + scol;
                __builtin_amdgcn_global_load_lds((g_u32*)gb,
                    (l_u32*)((char*)Bs[cur ^ 1] + r * 4096 + wbase), 16, 0, 0);
            }
        }
        // compute current buffer: one K=32 sub-step, 8 ds_read_b128 + 16 MFMA
        {
            short8_t a[4], b[4];
#pragma unroll
            for (int m = 0; m < 4; ++m)
                a[m] = *(const short8_t*)&As[cur][(wm * 64 + m * 16 + lr) * 32 + lk8];
#pragma unroll
            for (int n = 0; n < 4; ++n)
                b[n] = *(const short8_t*)&Bs[cur][(wn * 64 + n * 16 + lr) * 32 + lk8];
#pragma unroll
            for (int m = 0; m < 4; ++m)
#pragma unroll
                for (int n = 0; n < 4; ++n)
                    acc[m][n] = __builtin_amdgcn_mfma_f32_16x16x32_bf16(a[m], b[n], acc[m][n], 0, 0, 0);
        }
        // one barrier per step: drains next-tile loads (vmcnt) after compute,
        // and protects buf[cur] from restage next iteration.
        __syncthreads();
    }

    // epilogue: 7-bit quantize + byte store (row=(lane>>4)*4+q, col=lane&15)
    const int orow = (lane >> 4) * 4;
    const int ocol = lane & 15;
#pragma unroll
    for (int m = 0; m < 4; ++m)
#pragma unroll
        for (int q = 0; q < 4; ++q) {
            const int irow = i0 + wm * 64 + m * 16 + orow + q;
#pragma unroll
            for (int n = 0; n < 4; ++n) {
                float d = (1.0f - acc[m][n][q]) * 0.5f;
                d = fminf(fmaxf(d, 0.0f), 1.0f);
                unsigned key = __float2uint_rn(d * 127.0f);
                dist8[(size_t)irow * NROW + (j0 + wn * 64 + n * 16 + ocol)] = (unsigned char)key;
            }
        }
}

// ---------------------------------------------------------------------------
// Kernel 3: per-row top-K on 7-bit keys (verified SWAR body, rounds 10/12),
// VGPR pin against rematerialization (round-9 lesson); diagonal key issued
// first so its latency hides under the 16 row loads.
// ---------------------------------------------------------------------------
__global__ __launch_bounds__(256) void select_kernel(const unsigned char* __restrict__ dist8,
                                                     float* __restrict__ loss) {
    const int tid  = threadIdx.x;
    const int lane = tid & 63;
    const int wid  = tid >> 6;
    const int row  = blockIdx.x * 4 + wid;

    const unsigned dku = (unsigned)dist8[(size_t)row * NROW + row];  // issue first

    const uint4* __restrict__ P = (const uint4*)(dist8 + (size_t)row * NROW);
    unsigned w[16];
#pragma unroll
    for (int i = 0; i < 4; ++i) {
        uint4 v = P[i * 64 + lane];
        w[4 * i + 0] = v.x; w[4 * i + 1] = v.y;
        w[4 * i + 2] = v.z; w[4 * i + 3] = v.w;
    }
    // pin into registers: compiler may no longer re-derive w[] from memory
#pragma unroll
    for (int i = 0; i < 16; ++i) asm volatile("" : "+v"(w[i]));

    const unsigned M = 0x80808080u;
    const unsigned zero = 0u;

    unsigned rs = 0;
#pragma unroll
    for (int i = 0; i < 16; ++i) rs = sad_u8(w[i], zero, rs);

    int lo1 = 0, hi1 = 128, clo = 0;   // min: largest T with cnt(<T) < K
    int lo2 = -1, hi2 = 127, chi = 0;  // max: smallest T with cnt(>T) < K
#pragma unroll 1
    for (int it = 0; it < 7; ++it) {
        const int mid1 = (lo1 + hi1) >> 1;
        const int mid2 = (lo2 + hi2) >> 1;
        const unsigned C1 = (unsigned)(127 + mid1) * 0x01010101u;
        const unsigned C2 = (unsigned)(128 + mid2) * 0x01010101u;
        unsigned a1 = 0, a2 = 0;
#pragma unroll
        for (int i = 0; i < 16; ++i) {
            a1 = sad_u8((C1 - w[i]) & M, zero, a1);
            a2 = sad_u8((C2 - w[i]) & M, zero, a2);
        }
        int cc = (int)((a1 >> 7) | ((a2 >> 7) << 16));
#pragma unroll
        for (int off = 32; off; off >>= 1) cc += __shfl_xor(cc, off, 64);
        cc = __builtin_amdgcn_readfirstlane(cc);
        const int c1 = (cc & 0xFFFF) - ((dku < (unsigned)mid1) ? 1 : 0);
        const int c2 = (4096 - (cc >> 16)) - (((int)dku > mid2) ? 1 : 0);
        if (c1 < KSEL) { lo1 = mid1; clo = c1; } else hi1 = mid1;
        if (c2 < KSEL) { hi2 = mid2; chi = c2; } else lo2 = mid2;
    }
    const int Tmin = lo1, Tmax = hi2;

    const unsigned CA = (unsigned)(127 + Tmin) * 0x01010101u;
    const unsigned CB = (unsigned)(128 + Tmax) * 0x01010101u;
    unsigned sA = 0, sB = 0;
#pragma unroll
    for (int i = 0; i < 16; ++i) {
        const unsigned mA = ((CA - w[i]) & M) >> 7;
        sA = sad_u8(w[i] & ((mA << 8) - mA), zero, sA);
        const unsigned mB = ((CB - w[i]) & M) >> 7;
        sB = sad_u8(w[i] & ((mB << 8) - mB), zero, sB);
    }
#pragma unroll
    for (int off = 32; off; off >>= 1) {
        rs += __shfl_xor(rs, off, 64);
        sA += __shfl_xor(sA, off, 64);
        sB += __shfl_xor(sB, off, 64);
    }

    const int sum_min_i = (int)sA - ((dku < (unsigned)Tmin) ? (int)dku : 0)
                        + (KSEL - clo) * Tmin;
    const int sum_gt    = (int)(rs - sB);
    const int sum_max_i = sum_gt - (((int)dku > Tmax) ? (int)dku : 0)
                        + (KSEL - chi) * Tmax;

    if (lane == 0) {
        const float inv = 1.0f / 127.0f;
        const float total = (float)(sum_min_i + sum_max_i) * inv;
        const float dap = (float)dku * inv;
        const float neg = -0.0125f * total;  // -((1-prior)/(2K)) * sum
        const float pos = 0.5f * dap;        // prior * dist_ap
        loss[row] = (neg < 0.f) ? -neg : (pos + neg);
    }
}

// ---------------------------------------------------------------------------
// Kernel 4: deterministic mean of loss[0..N-1] -> out[0]
// ---------------------------------------------------------------------------
__global__ __launch_bounds__(256) void finalize_kernel(const float* __restrict__ loss,
                                                       float* __restrict__ out) {
    const int tid = threadIdx.x;
    float s = 0.f;
    for (int k = tid; k < NROW; k += 256) s += loss[k];
#pragma unroll
    for (int off = 32; off; off >>= 1) s += __shfl_xor(s, off, 64);
    __shared__ float p[4];
    if ((tid & 63) == 0) p[tid >> 6] = s;
    __syncthreads();
    if (tid == 0) out[0] = (p[0] + p[1] + p[2] + p[3]) * (1.0f / (float)NROW);
}

// ---------------------------------------------------------------------------
extern "C" void kernel_launch(void* const* d_in, const int* in_sizes, int n_in,
                              void* d_out, int out_size, void* d_ws, size_t ws_size,
                              hipStream_t stream) {
    const float* A = (const float*)d_in[0];  // input  [N,C] f32
    const float* B = (const float*)d_in[1];  // target [N,C] f32

    char* ws = (char*)d_ws;
    const size_t norm_bytes = (size_t)NROW * CDIM * 2;   // 2 MB each
    ushort* An = (ushort*)ws;
    ushort* Bn = (ushort*)(ws + norm_bytes);
    float*  lossv = (float*)(ws + 2 * norm_bytes);                    // 16 KB
    unsigned char* dist8 = (unsigned char*)(ws + 2 * norm_bytes + (size_t)NROW * 4);
    float* outp = (float*)d_out;

    prep_kernel<<<2 * NROW / 4, 256, 0, stream>>>(A, B, An, Bn);
    gemm16_kernel<<<1024, 256, 0, stream>>>(An, Bn, dist8);
    select_kernel<<<NROW / 4, 256, 0, stream>>>(dist8, lossv);
    finalize_kernel<<<1, 256, 0, stream>>>(lossv, outp);
}